// Round 14
// baseline (392.231 us; speedup 1.0000x reference)
//
#include <hip/hip_runtime.h>
#include <hip/hip_fp16.h>

// ---------------------------------------------------------------------------
// FormulaNet GCN forward: 3x GCNConv(128) + mean-pool(512 graphs) + dense.
// R2: fp16 node tensors (fp32 math). R4: bucket-sort CSR. R6: MFMA mm.
// R7: prep mega-kernel. R8: deep fusion (aggmm/aggsum). R10: paired-edge
// gathers. R12: aggsum block pooling via private LDS slots. [BEST 368.8]
// R13: agg blocks reshaped 256thr/4waves/4-serial-nodes ->
//      1024thr/16waves/2-serial-nodes (32 nodes/block):
//      - serial gather chain halved -> ~2x concurrent misses/CU;
//        occupancy 72% -> ~95% (VGPR 28, LDS 17.4 KB allow 32 waves/CU).
//      - MFMA: 32x128 out = 16 16x16 tiles = exactly 1 tile/wave.
//      Rationale: R2's standalone agg ran 0.30 us/MB-of-fill vs fused 0.41;
//      FETCH (201 MB = 8 XCD x 25.6 MB) is compulsory, rate is the knob.
// ---------------------------------------------------------------------------

#define BSHIFT 8
#define BSZ    256          // nodes per bucket
#define MAXBKT 512          // LDS sizing bound (N <= 131072)
#define CPAD   32           // 1 counter / 128 B line for global cursors
#define CAPSH  13           // 8192 staged/col slots per bucket

typedef _Float16 half8 __attribute__((ext_vector_type(8)));
typedef float f32x4 __attribute__((ext_vector_type(4)));

#define RFL __builtin_amdgcn_readfirstlane

// ---- prep: bin | layer1 | cvtW | bounds | zero(sums), by block range ----
__global__ __launch_bounds__(512) void k_prep(
        const float* __restrict__ x, const float* __restrict__ Wd1,
        const float* __restrict__ bd1, const float* __restrict__ Wg1,
        __half* __restrict__ g,
        const float* __restrict__ W2, const float* __restrict__ W3,
        __half* __restrict__ WT2, __half* __restrict__ WT3,
        const int* __restrict__ batch, int* __restrict__ gs,
        const int* __restrict__ src, const int* __restrict__ dst,
        int* __restrict__ bktFill, int* __restrict__ staged,
        float* __restrict__ sums,
        int N, int NG, int E, int nbkt, int BINB, int L1B, int NB1) {
    __shared__ float sW[512];
    __shared__ int hh[MAXBKT], base[MAXBKT], cur[MAXBKT];
    int bid = blockIdx.x;
    int t = threadIdx.x;
    if (bid < BINB) {
        // ---- bin: LDS hist -> one reservation/bucket -> staged scatter
        for (int i = t; i < nbkt; i += 512) { hh[i] = 0; cur[i] = 0; }
        __syncthreads();
        int e0 = bid * 4096 + t;
#pragma unroll
        for (int k = 0; k < 8; k++) {
            int e = e0 + k * 512;
            if (e < E) atomicAdd(&hh[dst[e] >> BSHIFT], 1);
        }
        __syncthreads();
        for (int i = t; i < nbkt; i += 512)
            base[i] = hh[i] ? atomicAdd(&bktFill[(size_t)i * CPAD], hh[i]) : 0;
        __syncthreads();
#pragma unroll
        for (int k = 0; k < 8; k++) {
            int e = e0 + k * 512;
            if (e < E) {
                int d = dst[e], s = src[e];
                int b = d >> BSHIFT;
                int off = atomicAdd(&cur[b], 1);
                staged[((size_t)b << CAPSH) + base[b] + off] =
                    ((d & (BSZ - 1)) << 17) | s;
            }
        }
    } else if (bid < BINB + L1B) {
        // ---- layer1: h0 = relu(x@Wd1+bd1); g = h0@Wg1 (fp16, bias deferred)
        int rb = bid - BINB;
        sW[t] = Wg1[t];
        __syncthreads();
        int j = t & 127;
        int node = rb * 4 + (t >> 7);
        if (node >= N) return;
        float4 xv = ((const float4*)x)[node];
        float acc = 0.f;
#pragma unroll
        for (int k = 0; k < 4; k++) {
            float h0 = xv.x * Wd1[k] + xv.y * Wd1[4 + k] + xv.z * Wd1[8 + k]
                     + xv.w * Wd1[12 + k] + bd1[k];
            h0 = fmaxf(h0, 0.f);
            acc = fmaf(h0, sW[k * 128 + j], acc);
        }
        g[(size_t)node * 128 + j] = __float2half_rn(acc);
    } else if (bid < BINB + L1B + 32) {
        // ---- cvtW: W fp32 [k][n] -> WT fp16 [n][k], both layers
        int t2 = (bid - BINB - L1B) * 512 + t;      // 0..16383
        int k = t2 >> 7, nn = t2 & 127;
        WT2[nn * 128 + k] = __float2half_rn(W2[t2]);
        WT3[nn * 128 + k] = __float2half_rn(W3[t2]);
    } else if (bid < BINB + L1B + 32 + NB1) {
        // ---- bounds: batch sorted -> per-graph node ranges
        int i = (bid - BINB - L1B - 32) * 512 + t;
        if (i >= N) return;
        int b = batch[i];
        int prev = (i == 0) ? -1 : batch[i - 1];
        for (int g2 = prev + 1; g2 <= b; ++g2) gs[g2] = i;
        if (i == N - 1)
            for (int g2 = b + 1; g2 <= NG; ++g2) gs[g2] = N;
    } else {
        // ---- zero sums
        int idx = (bid - BINB - L1B - 32 - NB1) * 512 + t;
        if (idx < NG * 128) sums[idx] = 0.f;
    }
}

// ---- per-bucket: hist -> deg/rpe/dis, LDS scan, window-local scatter ----
__global__ __launch_bounds__(512) void k_fineB(
        const int* __restrict__ staged, const int* __restrict__ bktFill,
        int2* __restrict__ rpe, float* __restrict__ dis,
        int* __restrict__ col, int N) {
    __shared__ int cnt[BSZ];
    __shared__ int incl[BSZ];
    int b = blockIdx.x;
    int lo = b << CAPSH;
    int cntE = bktFill[(size_t)b * CPAD];
    int n0 = b << BSHIFT;
    int tid = threadIdx.x;
    if (tid < BSZ) cnt[tid] = 0;
    __syncthreads();
    for (int e = tid; e < cntE; e += 512)
        atomicAdd(&cnt[staged[lo + e] >> 17], 1);
    __syncthreads();
    int v = 0;
    if (tid < BSZ) { v = cnt[tid]; incl[tid] = v; }
    for (int off = 1; off < BSZ; off <<= 1) {
        __syncthreads();
        int t = (tid < BSZ && tid >= off) ? incl[tid - off] : 0;
        __syncthreads();
        if (tid < BSZ) incl[tid] += t;
    }
    __syncthreads();
    int myofs = 0;
    if (tid < BSZ) {
        myofs = incl[tid] - v;                 // exclusive
        int node = n0 + tid;
        if (node < N) {
            rpe[node] = make_int2(lo + myofs, lo + myofs + v);
            dis[node] = rsqrtf((float)(v + 1));    // +1: self-loop
        }
    }
    __syncthreads();
    // reuse incl[] as base table, cnt[] as cursors
    if (tid < BSZ) { incl[tid] = myofs; cnt[tid] = 0; }
    __syncthreads();
    for (int e = tid; e < cntE; e += 512) {
        int ent = staged[lo + e];
        int dl = ent >> 17;
        int pos = lo + incl[dl] + atomicAdd(&cnt[dl], 1);
        col[pos] = ent & 0x1FFFF;
    }
}

// paired-edge aggregation: half-wave hf covers edge e+hf's FULL row
// (8 B/lane = ushort4, lanes sl=0..31 -> feats 4sl..4sl+3).
// After the loop, shfl_xor(32) combines halves; all lanes hold the sum.
__device__ __forceinline__ void agg_node4(
        const __half* __restrict__ g, const int* __restrict__ col,
        const float* __restrict__ dis, int r0, int r1, int node,
        float di, int hf, int sl, float acc[4]) {
    uint2 mr = *(const uint2*)(g + (size_t)node * 128 + sl * 4);
    float2 m01 = __half22float2(*(__half2*)&mr.x);
    float2 m23 = __half22float2(*(__half2*)&mr.y);
    float sw = hf ? 0.f : di;               // self-loop on half 0 only
    acc[0] = sw * m01.x; acc[1] = sw * m01.y;
    acc[2] = sw * m23.x; acc[3] = sw * m23.y;
    int e = r0;
    for (; e + 7 < r1; e += 8) {            // 4 pairs in flight
        int sa0 = RFL(col[e]),     sb0 = RFL(col[e + 1]);
        int sa1 = RFL(col[e + 2]), sb1 = RFL(col[e + 3]);
        int sa2 = RFL(col[e + 4]), sb2 = RFL(col[e + 5]);
        int sa3 = RFL(col[e + 6]), sb3 = RFL(col[e + 7]);
        float wa0 = dis[sa0], wb0 = dis[sb0], wa1 = dis[sa1], wb1 = dis[sb1];
        float wa2 = dis[sa2], wb2 = dis[sb2], wa3 = dis[sa3], wb3 = dis[sb3];
        int   s0 = hf ? sb0 : sa0; float w0 = hf ? wb0 : wa0;
        int   s1 = hf ? sb1 : sa1; float w1 = hf ? wb1 : wa1;
        int   s2 = hf ? sb2 : sa2; float w2 = hf ? wb2 : wa2;
        int   s3 = hf ? sb3 : sa3; float w3 = hf ? wb3 : wa3;
        uint2 r0v = *(const uint2*)(g + (size_t)s0 * 128 + sl * 4);
        uint2 r1v = *(const uint2*)(g + (size_t)s1 * 128 + sl * 4);
        uint2 r2v = *(const uint2*)(g + (size_t)s2 * 128 + sl * 4);
        uint2 r3v = *(const uint2*)(g + (size_t)s3 * 128 + sl * 4);
        float2 a01, a23;
        a01 = __half22float2(*(__half2*)&r0v.x); a23 = __half22float2(*(__half2*)&r0v.y);
        acc[0] = fmaf(w0, a01.x, acc[0]); acc[1] = fmaf(w0, a01.y, acc[1]);
        acc[2] = fmaf(w0, a23.x, acc[2]); acc[3] = fmaf(w0, a23.y, acc[3]);
        a01 = __half22float2(*(__half2*)&r1v.x); a23 = __half22float2(*(__half2*)&r1v.y);
        acc[0] = fmaf(w1, a01.x, acc[0]); acc[1] = fmaf(w1, a01.y, acc[1]);
        acc[2] = fmaf(w1, a23.x, acc[2]); acc[3] = fmaf(w1, a23.y, acc[3]);
        a01 = __half22float2(*(__half2*)&r2v.x); a23 = __half22float2(*(__half2*)&r2v.y);
        acc[0] = fmaf(w2, a01.x, acc[0]); acc[1] = fmaf(w2, a01.y, acc[1]);
        acc[2] = fmaf(w2, a23.x, acc[2]); acc[3] = fmaf(w2, a23.y, acc[3]);
        a01 = __half22float2(*(__half2*)&r3v.x); a23 = __half22float2(*(__half2*)&r3v.y);
        acc[0] = fmaf(w3, a01.x, acc[0]); acc[1] = fmaf(w3, a01.y, acc[1]);
        acc[2] = fmaf(w3, a23.x, acc[2]); acc[3] = fmaf(w3, a23.y, acc[3]);
    }
    for (; e + 1 < r1; e += 2) {
        int sa = RFL(col[e]), sb = RFL(col[e + 1]);
        float wa = dis[sa], wb = dis[sb];
        int   s = hf ? sb : sa; float w = hf ? wb : wa;
        uint2 rv = *(const uint2*)(g + (size_t)s * 128 + sl * 4);
        float2 a01 = __half22float2(*(__half2*)&rv.x);
        float2 a23 = __half22float2(*(__half2*)&rv.y);
        acc[0] = fmaf(w, a01.x, acc[0]); acc[1] = fmaf(w, a01.y, acc[1]);
        acc[2] = fmaf(w, a23.x, acc[2]); acc[3] = fmaf(w, a23.y, acc[3]);
    }
    if (e < r1) {                           // odd tail: half 1 contributes 0
        int sa = RFL(col[e]);
        float wa = dis[sa];
        float w = hf ? 0.f : wa;
        uint2 rv = *(const uint2*)(g + (size_t)sa * 128 + sl * 4);
        float2 a01 = __half22float2(*(__half2*)&rv.x);
        float2 a23 = __half22float2(*(__half2*)&rv.y);
        acc[0] = fmaf(w, a01.x, acc[0]); acc[1] = fmaf(w, a01.y, acc[1]);
        acc[2] = fmaf(w, a23.x, acc[2]); acc[3] = fmaf(w, a23.y, acc[3]);
    }
#pragma unroll
    for (int k = 0; k < 4; k++) acc[k] += __shfl_xor(acc[k], 32);
}

// fused GCN layer: block = 32 nodes = 16 waves x 2 serial nodes.
// agg(+bias,relu) -> LDS rows -> MFMA: 32x128 out = 16 tiles of 16x16,
// exactly one tile per wave (rows0=(w&1)*16, cols0=(w>>1)*16).
__global__ __launch_bounds__(1024) void k_aggmm(
        const __half* __restrict__ gin, const int2* __restrict__ rpe,
        const int* __restrict__ col, const float* __restrict__ dis,
        const float* __restrict__ bias, const __half* __restrict__ WT,
        __half* __restrict__ gout, int n) {
    __shared__ _Float16 sH[32 * 136];
    __shared__ _Float16 sO[32 * 136];
    int t = threadIdx.x;
    int wave = t >> 6, lane = t & 63;
    int hf = lane >> 5, sl = lane & 31;
    float4 bb = ((const float4*)bias)[sl];
#pragma unroll
    for (int i = 0; i < 2; i++) {
        int node = RFL(blockIdx.x * 32 + wave * 2 + i);
        if (node < n) {
            int2 re = rpe[node];
            int r0 = RFL(re.x);
            int r1 = RFL(re.y);
            float di = dis[node];
            float acc[4];
            agg_node4(gin, col, dis, r0, r1, node, di, hf, sl, acc);
            if (hf == 0) {
                int lr = wave * 2 + i;
                __half2 o01 = __floats2half2_rn(
                    fmaxf(fmaf(di, acc[0], bb.x), 0.f),
                    fmaxf(fmaf(di, acc[1], bb.y), 0.f));
                __half2 o23 = __floats2half2_rn(
                    fmaxf(fmaf(di, acc[2], bb.z), 0.f),
                    fmaxf(fmaf(di, acc[3], bb.w), 0.f));
                uint2 pk;
                pk.x = *(unsigned*)&o01; pk.y = *(unsigned*)&o23;
                *(uint2*)&sH[lr * 136 + sl * 4] = pk;
            }
        }
    }
    __syncthreads();
    // mm: wave computes the 16x16 tile at (rows0, cols0)
    int q = lane >> 4, c = lane & 15;
    int rows0 = (wave & 1) * 16, cols0 = (wave >> 1) * 16;
    f32x4 acc = {0.f, 0.f, 0.f, 0.f};
#pragma unroll
    for (int ks = 0; ks < 4; ks++) {
        int k0 = ks * 32;
        half8 a = *(half8*)&sH[(rows0 + c) * 136 + k0 + q * 8];
        half8 b = *(const half8*)(WT + (size_t)(cols0 + c) * 128 + k0 + q * 8);
        acc = __builtin_amdgcn_mfma_f32_16x16x32_f16(a, b, acc, 0, 0, 0);
    }
#pragma unroll
    for (int r = 0; r < 4; r++)
        sO[(rows0 + q * 4 + r) * 136 + cols0 + c] = (_Float16)acc[r];
    __syncthreads();
    int lr2 = t >> 5, seg = t & 31;     // 32 rows x 32 segs of 4 halves
    int row = blockIdx.x * 32 + lr2;
    if (row < n)
        *(uint2*)(gout + (size_t)row * 128 + seg * 4) =
            *(uint2*)&sO[lr2 * 136 + seg * 4];
}

// fused layer-3 agg + mean-pool: block = 32 nodes = 16 waves x 2 nodes.
// Single-graph blocks: per-wave register partials -> private LDS slots ->
// one barrier -> 128 global atomics. Boundary blocks: per-wave flush.
__global__ __launch_bounds__(1024) void k_aggsum(
        const __half* __restrict__ gin, const int2* __restrict__ rpe,
        const int* __restrict__ col, const float* __restrict__ dis,
        const float* __restrict__ bias, const int* __restrict__ batch,
        float* __restrict__ sums, int n) {
    __shared__ float ls[16][128];
    int t = threadIdx.x;
    int wave = t >> 6, lane = t & 63;
    int hf = lane >> 5, sl = lane & 31;
    int nodeBase = blockIdx.x * 32;
    if (nodeBase >= n) return;
    int lastNode = min(nodeBase + 31, n - 1);
    int b0 = RFL(batch[nodeBase]);
    bool uni = (RFL(batch[lastNode]) == b0);
    float4 bb = ((const float4*)bias)[sl];
    float sx[4] = {0.f, 0.f, 0.f, 0.f};
    int curb = b0;
#pragma unroll
    for (int i = 0; i < 2; i++) {
        int node = RFL(nodeBase + wave * 2 + i);
        if (node < n) {
            int2 re = rpe[node];
            int r0 = RFL(re.x);
            int r1 = RFL(re.y);
            float di = dis[node];
            float acc[4];
            agg_node4(gin, col, dis, r0, r1, node, di, hf, sl, acc);
            float o0 = fmaxf(fmaf(di, acc[0], bb.x), 0.f);
            float o1 = fmaxf(fmaf(di, acc[1], bb.y), 0.f);
            float o2 = fmaxf(fmaf(di, acc[2], bb.z), 0.f);
            float o3 = fmaxf(fmaf(di, acc[3], bb.w), 0.f);
            if (!uni) {
                int b = RFL(batch[node]);
                if (b != curb) {
                    if (hf == 0) {
                        atomicAdd(&sums[(size_t)curb * 128 + sl * 4 + 0], sx[0]);
                        atomicAdd(&sums[(size_t)curb * 128 + sl * 4 + 1], sx[1]);
                        atomicAdd(&sums[(size_t)curb * 128 + sl * 4 + 2], sx[2]);
                        atomicAdd(&sums[(size_t)curb * 128 + sl * 4 + 3], sx[3]);
                    }
                    sx[0] = sx[1] = sx[2] = sx[3] = 0.f;
                    curb = b;
                }
            }
            sx[0] += o0; sx[1] += o1; sx[2] += o2; sx[3] += o3;
        }
    }
    if (uni) {
        if (hf == 0) {
            ls[wave][sl * 4 + 0] = sx[0];
            ls[wave][sl * 4 + 1] = sx[1];
            ls[wave][sl * 4 + 2] = sx[2];
            ls[wave][sl * 4 + 3] = sx[3];
        }
        __syncthreads();
        if (t < 128) {
            float v = 0.f;
#pragma unroll
            for (int w = 0; w < 16; w++) v += ls[w][t];
            atomicAdd(&sums[(size_t)b0 * 128 + t], v);
        }
    } else {
        if (hf == 0) {
            atomicAdd(&sums[(size_t)curb * 128 + sl * 4 + 0], sx[0]);
            atomicAdd(&sums[(size_t)curb * 128 + sl * 4 + 1], sx[1]);
            atomicAdd(&sums[(size_t)curb * 128 + sl * 4 + 2], sx[2]);
            atomicAdd(&sums[(size_t)curb * 128 + sl * 4 + 3], sx[3]);
        }
    }
}

// head: pooled = sums/cnt; out = pooled @ Wd2 + bd2. One block per graph.
__global__ __launch_bounds__(128) void k_head(
        const float* __restrict__ sums, const int* __restrict__ gs,
        const float* __restrict__ Wd2, const float* __restrict__ bd2,
        float* __restrict__ out) {
    int gidx = blockIdx.x;
    int j = threadIdx.x;
    int c = gs[gidx + 1] - gs[gidx];
    float inv = 1.0f / (float)(c > 1 ? c : 1);
    __shared__ float sp[128];
    sp[j] = sums[(size_t)gidx * 128 + j] * inv;
    __syncthreads();
    float o = bd2[j];
#pragma unroll 8
    for (int k = 0; k < 128; k++) o = fmaf(sp[k], Wd2[k * 128 + j], o);
    out[gidx * 128 + j] = o;
}

extern "C" void kernel_launch(void* const* d_in, const int* in_sizes, int n_in,
                              void* d_out, int out_size, void* d_ws, size_t ws_size,
                              hipStream_t stream) {
    const float* x   = (const float*)d_in[0];
    const int*  ei   = (const int*)d_in[1];
    const int* batch = (const int*)d_in[2];
    const float* Wd1 = (const float*)d_in[3];
    const float* bd1 = (const float*)d_in[4];
    const float* Wg1 = (const float*)d_in[5];
    const float* bg1 = (const float*)d_in[6];
    const float* Wg2 = (const float*)d_in[7];
    const float* bg2 = (const float*)d_in[8];
    const float* Wg3 = (const float*)d_in[9];
    const float* bg3 = (const float*)d_in[10];
    const float* Wd2 = (const float*)d_in[11];
    const float* bd2 = (const float*)d_in[12];
    float* out = (float*)d_out;

    int N  = in_sizes[0] / 4;       // N_FEAT = 4
    int E  = in_sizes[1] / 2;       // edge_index is [2, E]
    int NG = out_size / 128;        // 512 graphs
    const int* srcIdx = ei;
    const int* dstIdx = ei + E;
    int nbkt = (N + BSZ - 1) >> BSHIFT;     // 391 for N=100000

    char* p = (char*)d_ws;
    auto alloc = [&](size_t bytes) -> char* {
        char* r = p;
        p += (bytes + 255) & ~(size_t)255;
        return r;
    };
    int*    bktFill = (int*)alloc((size_t)nbkt * CPAD * 4);
    int*    staged  = (int*)alloc(((size_t)nbkt << CAPSH) * 4);   // 12.8 MB
    int*    col     = (int*)alloc(((size_t)nbkt << CAPSH) * 4);   // 12.8 MB
    int2*   rpe     = (int2*)alloc((size_t)N * 8);
    float*  dis     = (float*)alloc((size_t)N * 4);
    int*    gs      = (int*)alloc(((size_t)NG + 1) * 4);
    float*  sums    = (float*)alloc((size_t)NG * 128 * 4);
    __half* WT2     = (__half*)alloc(16384 * 2);
    __half* WT3     = (__half*)alloc(16384 * 2);
    __half* gA      = (__half*)alloc((size_t)N * 128 * 2);
    __half* gB      = (__half*)alloc((size_t)N * 128 * 2);
    (void)ws_size; (void)n_in;

    int BINB = (E + 4095) / 4096;               // 391
    int L1B  = (N + 3) / 4;                     // 25000
    int NB1  = (N + 511) / 512;                 // 196
    int ZB   = (NG * 128 + 511) / 512;          // 128
    int prepB = BINB + L1B + 32 + NB1 + ZB;
    int fb   = (N + 31) / 32;                   // 3125

    hipMemsetAsync(bktFill, 0, (size_t)nbkt * CPAD * 4, stream);  // 50 KB

    k_prep<<<prepB, 512, 0, stream>>>(x, Wd1, bd1, Wg1, gA, Wg2, Wg3, WT2, WT3,
                                      batch, gs, srcIdx, dstIdx, bktFill,
                                      staged, sums, N, NG, E, nbkt,
                                      BINB, L1B, NB1);
    k_fineB<<<nbkt, 512, 0, stream>>>(staged, bktFill, rpe, dis, col, N);

    k_aggmm<<<fb, 1024, 0, stream>>>(gA, rpe, col, dis, bg1, WT2, gB, N);
    k_aggmm<<<fb, 1024, 0, stream>>>(gB, rpe, col, dis, bg2, WT3, gA, N);
    k_aggsum<<<fb, 1024, 0, stream>>>(gA, rpe, col, dis, bg3, batch, sums, N);

    k_head<<<NG, 128, 0, stream>>>(sums, gs, Wd2, bd2, out);
}

// Round 15
// 377.120 us; speedup vs baseline: 1.0401x; 1.0401x over previous
//
#include <hip/hip_runtime.h>
#include <hip/hip_fp16.h>

// ---------------------------------------------------------------------------
// FormulaNet GCN forward: 3x GCNConv(128) + mean-pool(512 graphs) + dense.
// R2: fp16 node tensors (fp32 math). R4: bucket-sort CSR. R6: MFMA mm.
// R7: prep mega-kernel. R8: deep fusion (aggmm/aggsum). R10: paired-edge
// gathers. R12: aggsum block pooling via private LDS slots. [BEST 368.8]
// R13: 1024-thr/16-wave agg blocks [REGRESSION +23: 16-wave barrier gated by
//      slowest wave; occupancy 72->77 only. 4 waves x 4 nodes is the agg
//      local optimum — agg shape-space exhausted at ~82 us fused floor.]
// R14: exact R12 revert + bin section split 4096 -> 2048 edges/block
//      (391 -> 782 bin blocks, 1.5 -> 3 blocks/CU) — bin is k_prep's tail;
//      bucket geometry (BSHIFT 8) untouched to avoid the R11 confound.
// ---------------------------------------------------------------------------

#define BSHIFT 8
#define BSZ    256          // nodes per bucket
#define MAXBKT 512          // LDS sizing bound (N <= 131072)
#define CPAD   32           // 1 counter / 128 B line for global cursors
#define CAPSH  13           // 8192 staged/col slots per bucket

typedef _Float16 half8 __attribute__((ext_vector_type(8)));
typedef float f32x4 __attribute__((ext_vector_type(4)));

#define RFL __builtin_amdgcn_readfirstlane

// ---- prep: bin | layer1 | cvtW | bounds | zero(sums), by block range ----
__global__ __launch_bounds__(512) void k_prep(
        const float* __restrict__ x, const float* __restrict__ Wd1,
        const float* __restrict__ bd1, const float* __restrict__ Wg1,
        __half* __restrict__ g,
        const float* __restrict__ W2, const float* __restrict__ W3,
        __half* __restrict__ WT2, __half* __restrict__ WT3,
        const int* __restrict__ batch, int* __restrict__ gs,
        const int* __restrict__ src, const int* __restrict__ dst,
        int* __restrict__ bktFill, int* __restrict__ staged,
        float* __restrict__ sums,
        int N, int NG, int E, int nbkt, int BINB, int L1B, int NB1) {
    __shared__ float sW[512];
    __shared__ int hh[MAXBKT], base[MAXBKT], cur[MAXBKT];
    int bid = blockIdx.x;
    int t = threadIdx.x;
    if (bid < BINB) {
        // ---- bin: 2048 edges/block; LDS hist -> reservation -> scatter
        for (int i = t; i < nbkt; i += 512) { hh[i] = 0; cur[i] = 0; }
        __syncthreads();
        int e0 = bid * 2048 + t;
#pragma unroll
        for (int k = 0; k < 4; k++) {
            int e = e0 + k * 512;
            if (e < E) atomicAdd(&hh[dst[e] >> BSHIFT], 1);
        }
        __syncthreads();
        for (int i = t; i < nbkt; i += 512)
            base[i] = hh[i] ? atomicAdd(&bktFill[(size_t)i * CPAD], hh[i]) : 0;
        __syncthreads();
#pragma unroll
        for (int k = 0; k < 4; k++) {
            int e = e0 + k * 512;
            if (e < E) {
                int d = dst[e], s = src[e];
                int b = d >> BSHIFT;
                int off = atomicAdd(&cur[b], 1);
                staged[((size_t)b << CAPSH) + base[b] + off] =
                    ((d & (BSZ - 1)) << 17) | s;
            }
        }
    } else if (bid < BINB + L1B) {
        // ---- layer1: h0 = relu(x@Wd1+bd1); g = h0@Wg1 (fp16, bias deferred)
        int rb = bid - BINB;
        sW[t] = Wg1[t];
        __syncthreads();
        int j = t & 127;
        int node = rb * 4 + (t >> 7);
        if (node >= N) return;
        float4 xv = ((const float4*)x)[node];
        float acc = 0.f;
#pragma unroll
        for (int k = 0; k < 4; k++) {
            float h0 = xv.x * Wd1[k] + xv.y * Wd1[4 + k] + xv.z * Wd1[8 + k]
                     + xv.w * Wd1[12 + k] + bd1[k];
            h0 = fmaxf(h0, 0.f);
            acc = fmaf(h0, sW[k * 128 + j], acc);
        }
        g[(size_t)node * 128 + j] = __float2half_rn(acc);
    } else if (bid < BINB + L1B + 32) {
        // ---- cvtW: W fp32 [k][n] -> WT fp16 [n][k], both layers
        int t2 = (bid - BINB - L1B) * 512 + t;      // 0..16383
        int k = t2 >> 7, nn = t2 & 127;
        WT2[nn * 128 + k] = __float2half_rn(W2[t2]);
        WT3[nn * 128 + k] = __float2half_rn(W3[t2]);
    } else if (bid < BINB + L1B + 32 + NB1) {
        // ---- bounds: batch sorted -> per-graph node ranges
        int i = (bid - BINB - L1B - 32) * 512 + t;
        if (i >= N) return;
        int b = batch[i];
        int prev = (i == 0) ? -1 : batch[i - 1];
        for (int g2 = prev + 1; g2 <= b; ++g2) gs[g2] = i;
        if (i == N - 1)
            for (int g2 = b + 1; g2 <= NG; ++g2) gs[g2] = N;
    } else {
        // ---- zero sums
        int idx = (bid - BINB - L1B - 32 - NB1) * 512 + t;
        if (idx < NG * 128) sums[idx] = 0.f;
    }
}

// ---- per-bucket: hist -> deg/rpe/dis, LDS scan, window-local scatter ----
__global__ __launch_bounds__(512) void k_fineB(
        const int* __restrict__ staged, const int* __restrict__ bktFill,
        int2* __restrict__ rpe, float* __restrict__ dis,
        int* __restrict__ col, int N) {
    __shared__ int cnt[BSZ];
    __shared__ int incl[BSZ];
    int b = blockIdx.x;
    int lo = b << CAPSH;
    int cntE = bktFill[(size_t)b * CPAD];
    int n0 = b << BSHIFT;
    int tid = threadIdx.x;
    if (tid < BSZ) cnt[tid] = 0;
    __syncthreads();
    for (int e = tid; e < cntE; e += 512)
        atomicAdd(&cnt[staged[lo + e] >> 17], 1);
    __syncthreads();
    int v = 0;
    if (tid < BSZ) { v = cnt[tid]; incl[tid] = v; }
    for (int off = 1; off < BSZ; off <<= 1) {
        __syncthreads();
        int t = (tid < BSZ && tid >= off) ? incl[tid - off] : 0;
        __syncthreads();
        if (tid < BSZ) incl[tid] += t;
    }
    __syncthreads();
    int myofs = 0;
    if (tid < BSZ) {
        myofs = incl[tid] - v;                 // exclusive
        int node = n0 + tid;
        if (node < N) {
            rpe[node] = make_int2(lo + myofs, lo + myofs + v);
            dis[node] = rsqrtf((float)(v + 1));    // +1: self-loop
        }
    }
    __syncthreads();
    // reuse incl[] as base table, cnt[] as cursors
    if (tid < BSZ) { incl[tid] = myofs; cnt[tid] = 0; }
    __syncthreads();
    for (int e = tid; e < cntE; e += 512) {
        int ent = staged[lo + e];
        int dl = ent >> 17;
        int pos = lo + incl[dl] + atomicAdd(&cnt[dl], 1);
        col[pos] = ent & 0x1FFFF;
    }
}

// paired-edge aggregation: half-wave hf covers edge e+hf's FULL row
// (8 B/lane = ushort4, lanes sl=0..31 -> feats 4sl..4sl+3).
// After the loop, shfl_xor(32) combines halves; all lanes hold the sum.
__device__ __forceinline__ void agg_node4(
        const __half* __restrict__ g, const int* __restrict__ col,
        const float* __restrict__ dis, int r0, int r1, int node,
        float di, int hf, int sl, float acc[4]) {
    uint2 mr = *(const uint2*)(g + (size_t)node * 128 + sl * 4);
    float2 m01 = __half22float2(*(__half2*)&mr.x);
    float2 m23 = __half22float2(*(__half2*)&mr.y);
    float sw = hf ? 0.f : di;               // self-loop on half 0 only
    acc[0] = sw * m01.x; acc[1] = sw * m01.y;
    acc[2] = sw * m23.x; acc[3] = sw * m23.y;
    int e = r0;
    for (; e + 7 < r1; e += 8) {            // 4 pairs in flight
        int sa0 = RFL(col[e]),     sb0 = RFL(col[e + 1]);
        int sa1 = RFL(col[e + 2]), sb1 = RFL(col[e + 3]);
        int sa2 = RFL(col[e + 4]), sb2 = RFL(col[e + 5]);
        int sa3 = RFL(col[e + 6]), sb3 = RFL(col[e + 7]);
        float wa0 = dis[sa0], wb0 = dis[sb0], wa1 = dis[sa1], wb1 = dis[sb1];
        float wa2 = dis[sa2], wb2 = dis[sb2], wa3 = dis[sa3], wb3 = dis[sb3];
        int   s0 = hf ? sb0 : sa0; float w0 = hf ? wb0 : wa0;
        int   s1 = hf ? sb1 : sa1; float w1 = hf ? wb1 : wa1;
        int   s2 = hf ? sb2 : sa2; float w2 = hf ? wb2 : wa2;
        int   s3 = hf ? sb3 : sa3; float w3 = hf ? wb3 : wa3;
        uint2 r0v = *(const uint2*)(g + (size_t)s0 * 128 + sl * 4);
        uint2 r1v = *(const uint2*)(g + (size_t)s1 * 128 + sl * 4);
        uint2 r2v = *(const uint2*)(g + (size_t)s2 * 128 + sl * 4);
        uint2 r3v = *(const uint2*)(g + (size_t)s3 * 128 + sl * 4);
        float2 a01, a23;
        a01 = __half22float2(*(__half2*)&r0v.x); a23 = __half22float2(*(__half2*)&r0v.y);
        acc[0] = fmaf(w0, a01.x, acc[0]); acc[1] = fmaf(w0, a01.y, acc[1]);
        acc[2] = fmaf(w0, a23.x, acc[2]); acc[3] = fmaf(w0, a23.y, acc[3]);
        a01 = __half22float2(*(__half2*)&r1v.x); a23 = __half22float2(*(__half2*)&r1v.y);
        acc[0] = fmaf(w1, a01.x, acc[0]); acc[1] = fmaf(w1, a01.y, acc[1]);
        acc[2] = fmaf(w1, a23.x, acc[2]); acc[3] = fmaf(w1, a23.y, acc[3]);
        a01 = __half22float2(*(__half2*)&r2v.x); a23 = __half22float2(*(__half2*)&r2v.y);
        acc[0] = fmaf(w2, a01.x, acc[0]); acc[1] = fmaf(w2, a01.y, acc[1]);
        acc[2] = fmaf(w2, a23.x, acc[2]); acc[3] = fmaf(w2, a23.y, acc[3]);
        a01 = __half22float2(*(__half2*)&r3v.x); a23 = __half22float2(*(__half2*)&r3v.y);
        acc[0] = fmaf(w3, a01.x, acc[0]); acc[1] = fmaf(w3, a01.y, acc[1]);
        acc[2] = fmaf(w3, a23.x, acc[2]); acc[3] = fmaf(w3, a23.y, acc[3]);
    }
    for (; e + 1 < r1; e += 2) {
        int sa = RFL(col[e]), sb = RFL(col[e + 1]);
        float wa = dis[sa], wb = dis[sb];
        int   s = hf ? sb : sa; float w = hf ? wb : wa;
        uint2 rv = *(const uint2*)(g + (size_t)s * 128 + sl * 4);
        float2 a01 = __half22float2(*(__half2*)&rv.x);
        float2 a23 = __half22float2(*(__half2*)&rv.y);
        acc[0] = fmaf(w, a01.x, acc[0]); acc[1] = fmaf(w, a01.y, acc[1]);
        acc[2] = fmaf(w, a23.x, acc[2]); acc[3] = fmaf(w, a23.y, acc[3]);
    }
    if (e < r1) {                           // odd tail: half 1 contributes 0
        int sa = RFL(col[e]);
        float wa = dis[sa];
        float w = hf ? 0.f : wa;
        uint2 rv = *(const uint2*)(g + (size_t)sa * 128 + sl * 4);
        float2 a01 = __half22float2(*(__half2*)&rv.x);
        float2 a23 = __half22float2(*(__half2*)&rv.y);
        acc[0] = fmaf(w, a01.x, acc[0]); acc[1] = fmaf(w, a01.y, acc[1]);
        acc[2] = fmaf(w, a23.x, acc[2]); acc[3] = fmaf(w, a23.y, acc[3]);
    }
#pragma unroll
    for (int k = 0; k < 4; k++) acc[k] += __shfl_xor(acc[k], 32);
}

// fused GCN layer: block = 16 nodes (4 waves x 4 serial nodes).
// agg (+bias,relu) -> LDS rows -> mfma_f32_16x16x32_f16 -> gout (no bias).
__global__ __launch_bounds__(256) void k_aggmm(
        const __half* __restrict__ gin, const int2* __restrict__ rpe,
        const int* __restrict__ col, const float* __restrict__ dis,
        const float* __restrict__ bias, const __half* __restrict__ WT,
        __half* __restrict__ gout, int n) {
    __shared__ _Float16 sH[16 * 136];
    __shared__ _Float16 sO[16 * 136];
    int t = threadIdx.x;
    int wave = t >> 6, lane = t & 63;
    int hf = lane >> 5, sl = lane & 31;
    float4 bb = ((const float4*)bias)[sl];
#pragma unroll
    for (int i = 0; i < 4; i++) {
        int node = RFL(blockIdx.x * 16 + wave * 4 + i);
        if (node < n) {
            int2 re = rpe[node];
            int r0 = RFL(re.x);
            int r1 = RFL(re.y);
            float di = dis[node];
            float acc[4];
            agg_node4(gin, col, dis, r0, r1, node, di, hf, sl, acc);
            if (hf == 0) {
                int lr = wave * 4 + i;
                __half2 o01 = __floats2half2_rn(
                    fmaxf(fmaf(di, acc[0], bb.x), 0.f),
                    fmaxf(fmaf(di, acc[1], bb.y), 0.f));
                __half2 o23 = __floats2half2_rn(
                    fmaxf(fmaf(di, acc[2], bb.z), 0.f),
                    fmaxf(fmaf(di, acc[3], bb.w), 0.f));
                uint2 pk;
                pk.x = *(unsigned*)&o01; pk.y = *(unsigned*)&o23;
                *(uint2*)&sH[lr * 136 + sl * 4] = pk;
            }
        }
    }
    __syncthreads();
    // mm: wave covers cols [wave*32, wave*32+32) for all 16 rows
    int q = lane >> 4, c = lane & 15;
    int n0 = wave * 32;
    f32x4 acc0 = {0.f, 0.f, 0.f, 0.f}, acc1 = {0.f, 0.f, 0.f, 0.f};
#pragma unroll
    for (int ks = 0; ks < 4; ks++) {
        int k0 = ks * 32;
        half8 a  = *(half8*)&sH[c * 136 + k0 + q * 8];
        half8 b0 = *(const half8*)(WT + (size_t)(n0 + c) * 128 + k0 + q * 8);
        half8 b1 = *(const half8*)(WT + (size_t)(n0 + 16 + c) * 128 + k0 + q * 8);
        acc0 = __builtin_amdgcn_mfma_f32_16x16x32_f16(a, b0, acc0, 0, 0, 0);
        acc1 = __builtin_amdgcn_mfma_f32_16x16x32_f16(a, b1, acc1, 0, 0, 0);
    }
#pragma unroll
    for (int r = 0; r < 4; r++) {
        sO[(q * 4 + r) * 136 + n0 + c]      = (_Float16)acc0[r];
        sO[(q * 4 + r) * 136 + n0 + 16 + c] = (_Float16)acc1[r];
    }
    __syncthreads();
    int lr2 = t >> 4, seg = t & 15;
    int row = blockIdx.x * 16 + lr2;
    if (row < n)
        *(uint4*)(gout + (size_t)row * 128 + seg * 8) =
            *(uint4*)&sO[lr2 * 136 + seg * 8];
}

// fused layer-3 agg + mean-pool. Single-graph blocks (~92%): per-wave
// register partials -> private LDS slots (no LDS atomics) -> one barrier ->
// 128 global atomics per block. Boundary blocks: per-wave flush.
__global__ __launch_bounds__(256) void k_aggsum(
        const __half* __restrict__ gin, const int2* __restrict__ rpe,
        const int* __restrict__ col, const float* __restrict__ dis,
        const float* __restrict__ bias, const int* __restrict__ batch,
        float* __restrict__ sums, int n) {
    __shared__ float ls[4][128];
    int t = threadIdx.x;
    int wave = t >> 6, lane = t & 63;
    int hf = lane >> 5, sl = lane & 31;
    int nodeBase = blockIdx.x * 16;
    if (nodeBase >= n) return;
    int lastNode = min(nodeBase + 15, n - 1);
    int b0 = RFL(batch[nodeBase]);
    bool uni = (RFL(batch[lastNode]) == b0);
    float4 bb = ((const float4*)bias)[sl];
    float sx[4] = {0.f, 0.f, 0.f, 0.f};
    int curb = b0;
#pragma unroll
    for (int i = 0; i < 4; i++) {
        int node = RFL(nodeBase + wave * 4 + i);
        if (node < n) {
            int2 re = rpe[node];
            int r0 = RFL(re.x);
            int r1 = RFL(re.y);
            float di = dis[node];
            float acc[4];
            agg_node4(gin, col, dis, r0, r1, node, di, hf, sl, acc);
            float o0 = fmaxf(fmaf(di, acc[0], bb.x), 0.f);
            float o1 = fmaxf(fmaf(di, acc[1], bb.y), 0.f);
            float o2 = fmaxf(fmaf(di, acc[2], bb.z), 0.f);
            float o3 = fmaxf(fmaf(di, acc[3], bb.w), 0.f);
            if (!uni) {
                int b = RFL(batch[node]);
                if (b != curb) {
                    if (hf == 0) {
                        atomicAdd(&sums[(size_t)curb * 128 + sl * 4 + 0], sx[0]);
                        atomicAdd(&sums[(size_t)curb * 128 + sl * 4 + 1], sx[1]);
                        atomicAdd(&sums[(size_t)curb * 128 + sl * 4 + 2], sx[2]);
                        atomicAdd(&sums[(size_t)curb * 128 + sl * 4 + 3], sx[3]);
                    }
                    sx[0] = sx[1] = sx[2] = sx[3] = 0.f;
                    curb = b;
                }
            }
            sx[0] += o0; sx[1] += o1; sx[2] += o2; sx[3] += o3;
        }
    }
    if (uni) {
        // slot-exclusive LDS write (hf==0 lanes cover all 128 feats)
        if (hf == 0) {
            ls[wave][sl * 4 + 0] = sx[0];
            ls[wave][sl * 4 + 1] = sx[1];
            ls[wave][sl * 4 + 2] = sx[2];
            ls[wave][sl * 4 + 3] = sx[3];
        }
        __syncthreads();
        if (t < 128) {
            float v = ls[0][t] + ls[1][t] + ls[2][t] + ls[3][t];
            atomicAdd(&sums[(size_t)b0 * 128 + t], v);
        }
    } else {
        if (hf == 0) {
            atomicAdd(&sums[(size_t)curb * 128 + sl * 4 + 0], sx[0]);
            atomicAdd(&sums[(size_t)curb * 128 + sl * 4 + 1], sx[1]);
            atomicAdd(&sums[(size_t)curb * 128 + sl * 4 + 2], sx[2]);
            atomicAdd(&sums[(size_t)curb * 128 + sl * 4 + 3], sx[3]);
        }
    }
}

// head: pooled = sums/cnt; out = pooled @ Wd2 + bd2. One block per graph.
__global__ __launch_bounds__(128) void k_head(
        const float* __restrict__ sums, const int* __restrict__ gs,
        const float* __restrict__ Wd2, const float* __restrict__ bd2,
        float* __restrict__ out) {
    int gidx = blockIdx.x;
    int j = threadIdx.x;
    int c = gs[gidx + 1] - gs[gidx];
    float inv = 1.0f / (float)(c > 1 ? c : 1);
    __shared__ float sp[128];
    sp[j] = sums[(size_t)gidx * 128 + j] * inv;
    __syncthreads();
    float o = bd2[j];
#pragma unroll 8
    for (int k = 0; k < 128; k++) o = fmaf(sp[k], Wd2[k * 128 + j], o);
    out[gidx * 128 + j] = o;
}

extern "C" void kernel_launch(void* const* d_in, const int* in_sizes, int n_in,
                              void* d_out, int out_size, void* d_ws, size_t ws_size,
                              hipStream_t stream) {
    const float* x   = (const float*)d_in[0];
    const int*  ei   = (const int*)d_in[1];
    const int* batch = (const int*)d_in[2];
    const float* Wd1 = (const float*)d_in[3];
    const float* bd1 = (const float*)d_in[4];
    const float* Wg1 = (const float*)d_in[5];
    const float* bg1 = (const float*)d_in[6];
    const float* Wg2 = (const float*)d_in[7];
    const float* bg2 = (const float*)d_in[8];
    const float* Wg3 = (const float*)d_in[9];
    const float* bg3 = (const float*)d_in[10];
    const float* Wd2 = (const float*)d_in[11];
    const float* bd2 = (const float*)d_in[12];
    float* out = (float*)d_out;

    int N  = in_sizes[0] / 4;       // N_FEAT = 4
    int E  = in_sizes[1] / 2;       // edge_index is [2, E]
    int NG = out_size / 128;        // 512 graphs
    const int* srcIdx = ei;
    const int* dstIdx = ei + E;
    int nbkt = (N + BSZ - 1) >> BSHIFT;     // 391 for N=100000

    char* p = (char*)d_ws;
    auto alloc = [&](size_t bytes) -> char* {
        char* r = p;
        p += (bytes + 255) & ~(size_t)255;
        return r;
    };
    int*    bktFill = (int*)alloc((size_t)nbkt * CPAD * 4);
    int*    staged  = (int*)alloc(((size_t)nbkt << CAPSH) * 4);   // 12.8 MB
    int*    col     = (int*)alloc(((size_t)nbkt << CAPSH) * 4);   // 12.8 MB
    int2*   rpe     = (int2*)alloc((size_t)N * 8);
    float*  dis     = (float*)alloc((size_t)N * 4);
    int*    gs      = (int*)alloc(((size_t)NG + 1) * 4);
    float*  sums    = (float*)alloc((size_t)NG * 128 * 4);
    __half* WT2     = (__half*)alloc(16384 * 2);
    __half* WT3     = (__half*)alloc(16384 * 2);
    __half* gA      = (__half*)alloc((size_t)N * 128 * 2);
    __half* gB      = (__half*)alloc((size_t)N * 128 * 2);
    (void)ws_size; (void)n_in;

    int BINB = (E + 2047) / 2048;               // 782
    int L1B  = (N + 3) / 4;                     // 25000
    int NB1  = (N + 511) / 512;                 // 196
    int ZB   = (NG * 128 + 511) / 512;          // 128
    int prepB = BINB + L1B + 32 + NB1 + ZB;
    int fb   = (N + 15) / 16;                   // 6250

    hipMemsetAsync(bktFill, 0, (size_t)nbkt * CPAD * 4, stream);  // 50 KB

    k_prep<<<prepB, 512, 0, stream>>>(x, Wd1, bd1, Wg1, gA, Wg2, Wg3, WT2, WT3,
                                      batch, gs, srcIdx, dstIdx, bktFill,
                                      staged, sums, N, NG, E, nbkt,
                                      BINB, L1B, NB1);
    k_fineB<<<nbkt, 512, 0, stream>>>(staged, bktFill, rpe, dis, col, N);

    k_aggmm<<<fb, 256, 0, stream>>>(gA, rpe, col, dis, bg1, WT2, gB, N);
    k_aggmm<<<fb, 256, 0, stream>>>(gB, rpe, col, dis, bg2, WT3, gA, N);
    k_aggsum<<<fb, 256, 0, stream>>>(gA, rpe, col, dis, bg3, batch, sums, N);

    k_head<<<NG, 128, 0, stream>>>(sums, gs, Wd2, bd2, out);
}

// Round 16
// 359.317 us; speedup vs baseline: 1.0916x; 1.0495x over previous
//
#include <hip/hip_runtime.h>
#include <hip/hip_fp16.h>

// ---------------------------------------------------------------------------
// FormulaNet GCN forward: 3x GCNConv(128) + mean-pool(512 graphs) + dense.
// R2: fp16 node tensors (fp32 math). R4: bucket-sort CSR. R6: MFMA mm.
// R7: prep mega-kernel. R8: deep fusion (aggmm/aggsum). R10: paired-edge
// gathers. R12: aggsum block pooling via private LDS slots. [BEST 368.8]
// R13: 16-wave agg blocks [REGR +23: barrier imbalance]. R14: bin 2048
//      edges/block [REGR +8: doubled per-block fixed cost (zero+reserve over
//      all 391 slots); bin's 4096 shape was already right].
// R15: exact R12 revert + layer1 amortization: 64 nodes/block (16-iter loop,
//      25000 -> 1563 blocks) — one Wg1 LDS stage + barrier per 64 nodes
//      instead of per 4. Agg family is at its fused floor (FETCH = compulsory
//      201 MB/layer = 8 XCD x 25.6 MB; fill ~2.8 TB/s, shape-space exhausted).
// ---------------------------------------------------------------------------

#define BSHIFT 8
#define BSZ    256          // nodes per bucket
#define MAXBKT 512          // LDS sizing bound (N <= 131072)
#define CPAD   32           // 1 counter / 128 B line for global cursors
#define CAPSH  13           // 8192 staged/col slots per bucket

typedef _Float16 half8 __attribute__((ext_vector_type(8)));
typedef float f32x4 __attribute__((ext_vector_type(4)));

#define RFL __builtin_amdgcn_readfirstlane

// ---- prep: bin | layer1 | cvtW | bounds | zero(sums), by block range ----
__global__ __launch_bounds__(512) void k_prep(
        const float* __restrict__ x, const float* __restrict__ Wd1,
        const float* __restrict__ bd1, const float* __restrict__ Wg1,
        __half* __restrict__ g,
        const float* __restrict__ W2, const float* __restrict__ W3,
        __half* __restrict__ WT2, __half* __restrict__ WT3,
        const int* __restrict__ batch, int* __restrict__ gs,
        const int* __restrict__ src, const int* __restrict__ dst,
        int* __restrict__ bktFill, int* __restrict__ staged,
        float* __restrict__ sums,
        int N, int NG, int E, int nbkt, int BINB, int L1B, int NB1) {
    __shared__ float sW[512];
    __shared__ int hh[MAXBKT], base[MAXBKT], cur[MAXBKT];
    int bid = blockIdx.x;
    int t = threadIdx.x;
    if (bid < BINB) {
        // ---- bin: 4096 edges/block; LDS hist -> reservation -> scatter
        for (int i = t; i < nbkt; i += 512) { hh[i] = 0; cur[i] = 0; }
        __syncthreads();
        int e0 = bid * 4096 + t;
#pragma unroll
        for (int k = 0; k < 8; k++) {
            int e = e0 + k * 512;
            if (e < E) atomicAdd(&hh[dst[e] >> BSHIFT], 1);
        }
        __syncthreads();
        for (int i = t; i < nbkt; i += 512)
            base[i] = hh[i] ? atomicAdd(&bktFill[(size_t)i * CPAD], hh[i]) : 0;
        __syncthreads();
#pragma unroll
        for (int k = 0; k < 8; k++) {
            int e = e0 + k * 512;
            if (e < E) {
                int d = dst[e], s = src[e];
                int b = d >> BSHIFT;
                int off = atomicAdd(&cur[b], 1);
                staged[((size_t)b << CAPSH) + base[b] + off] =
                    ((d & (BSZ - 1)) << 17) | s;
            }
        }
    } else if (bid < BINB + L1B) {
        // ---- layer1: 64 nodes/block; h0 = relu(x@Wd1+bd1); g = h0@Wg1
        int rb = bid - BINB;
        sW[t] = Wg1[t];
        __syncthreads();
        int j = t & 127;
#pragma unroll 4
        for (int it = 0; it < 16; ++it) {
            int node = rb * 64 + it * 4 + (t >> 7);
            if (node < N) {
                float4 xv = ((const float4*)x)[node];
                float acc = 0.f;
#pragma unroll
                for (int k = 0; k < 4; k++) {
                    float h0 = xv.x * Wd1[k] + xv.y * Wd1[4 + k]
                             + xv.z * Wd1[8 + k] + xv.w * Wd1[12 + k] + bd1[k];
                    h0 = fmaxf(h0, 0.f);
                    acc = fmaf(h0, sW[k * 128 + j], acc);
                }
                g[(size_t)node * 128 + j] = __float2half_rn(acc);
            }
        }
    } else if (bid < BINB + L1B + 32) {
        // ---- cvtW: W fp32 [k][n] -> WT fp16 [n][k], both layers
        int t2 = (bid - BINB - L1B) * 512 + t;      // 0..16383
        int k = t2 >> 7, nn = t2 & 127;
        WT2[nn * 128 + k] = __float2half_rn(W2[t2]);
        WT3[nn * 128 + k] = __float2half_rn(W3[t2]);
    } else if (bid < BINB + L1B + 32 + NB1) {
        // ---- bounds: batch sorted -> per-graph node ranges
        int i = (bid - BINB - L1B - 32) * 512 + t;
        if (i >= N) return;
        int b = batch[i];
        int prev = (i == 0) ? -1 : batch[i - 1];
        for (int g2 = prev + 1; g2 <= b; ++g2) gs[g2] = i;
        if (i == N - 1)
            for (int g2 = b + 1; g2 <= NG; ++g2) gs[g2] = N;
    } else {
        // ---- zero sums
        int idx = (bid - BINB - L1B - 32 - NB1) * 512 + t;
        if (idx < NG * 128) sums[idx] = 0.f;
    }
}

// ---- per-bucket: hist -> deg/rpe/dis, LDS scan, window-local scatter ----
__global__ __launch_bounds__(512) void k_fineB(
        const int* __restrict__ staged, const int* __restrict__ bktFill,
        int2* __restrict__ rpe, float* __restrict__ dis,
        int* __restrict__ col, int N) {
    __shared__ int cnt[BSZ];
    __shared__ int incl[BSZ];
    int b = blockIdx.x;
    int lo = b << CAPSH;
    int cntE = bktFill[(size_t)b * CPAD];
    int n0 = b << BSHIFT;
    int tid = threadIdx.x;
    if (tid < BSZ) cnt[tid] = 0;
    __syncthreads();
    for (int e = tid; e < cntE; e += 512)
        atomicAdd(&cnt[staged[lo + e] >> 17], 1);
    __syncthreads();
    int v = 0;
    if (tid < BSZ) { v = cnt[tid]; incl[tid] = v; }
    for (int off = 1; off < BSZ; off <<= 1) {
        __syncthreads();
        int t = (tid < BSZ && tid >= off) ? incl[tid - off] : 0;
        __syncthreads();
        if (tid < BSZ) incl[tid] += t;
    }
    __syncthreads();
    int myofs = 0;
    if (tid < BSZ) {
        myofs = incl[tid] - v;                 // exclusive
        int node = n0 + tid;
        if (node < N) {
            rpe[node] = make_int2(lo + myofs, lo + myofs + v);
            dis[node] = rsqrtf((float)(v + 1));    // +1: self-loop
        }
    }
    __syncthreads();
    // reuse incl[] as base table, cnt[] as cursors
    if (tid < BSZ) { incl[tid] = myofs; cnt[tid] = 0; }
    __syncthreads();
    for (int e = tid; e < cntE; e += 512) {
        int ent = staged[lo + e];
        int dl = ent >> 17;
        int pos = lo + incl[dl] + atomicAdd(&cnt[dl], 1);
        col[pos] = ent & 0x1FFFF;
    }
}

// paired-edge aggregation: half-wave hf covers edge e+hf's FULL row
// (8 B/lane = ushort4, lanes sl=0..31 -> feats 4sl..4sl+3).
// After the loop, shfl_xor(32) combines halves; all lanes hold the sum.
__device__ __forceinline__ void agg_node4(
        const __half* __restrict__ g, const int* __restrict__ col,
        const float* __restrict__ dis, int r0, int r1, int node,
        float di, int hf, int sl, float acc[4]) {
    uint2 mr = *(const uint2*)(g + (size_t)node * 128 + sl * 4);
    float2 m01 = __half22float2(*(__half2*)&mr.x);
    float2 m23 = __half22float2(*(__half2*)&mr.y);
    float sw = hf ? 0.f : di;               // self-loop on half 0 only
    acc[0] = sw * m01.x; acc[1] = sw * m01.y;
    acc[2] = sw * m23.x; acc[3] = sw * m23.y;
    int e = r0;
    for (; e + 7 < r1; e += 8) {            // 4 pairs in flight
        int sa0 = RFL(col[e]),     sb0 = RFL(col[e + 1]);
        int sa1 = RFL(col[e + 2]), sb1 = RFL(col[e + 3]);
        int sa2 = RFL(col[e + 4]), sb2 = RFL(col[e + 5]);
        int sa3 = RFL(col[e + 6]), sb3 = RFL(col[e + 7]);
        float wa0 = dis[sa0], wb0 = dis[sb0], wa1 = dis[sa1], wb1 = dis[sb1];
        float wa2 = dis[sa2], wb2 = dis[sb2], wa3 = dis[sa3], wb3 = dis[sb3];
        int   s0 = hf ? sb0 : sa0; float w0 = hf ? wb0 : wa0;
        int   s1 = hf ? sb1 : sa1; float w1 = hf ? wb1 : wa1;
        int   s2 = hf ? sb2 : sa2; float w2 = hf ? wb2 : wa2;
        int   s3 = hf ? sb3 : sa3; float w3 = hf ? wb3 : wa3;
        uint2 r0v = *(const uint2*)(g + (size_t)s0 * 128 + sl * 4);
        uint2 r1v = *(const uint2*)(g + (size_t)s1 * 128 + sl * 4);
        uint2 r2v = *(const uint2*)(g + (size_t)s2 * 128 + sl * 4);
        uint2 r3v = *(const uint2*)(g + (size_t)s3 * 128 + sl * 4);
        float2 a01, a23;
        a01 = __half22float2(*(__half2*)&r0v.x); a23 = __half22float2(*(__half2*)&r0v.y);
        acc[0] = fmaf(w0, a01.x, acc[0]); acc[1] = fmaf(w0, a01.y, acc[1]);
        acc[2] = fmaf(w0, a23.x, acc[2]); acc[3] = fmaf(w0, a23.y, acc[3]);
        a01 = __half22float2(*(__half2*)&r1v.x); a23 = __half22float2(*(__half2*)&r1v.y);
        acc[0] = fmaf(w1, a01.x, acc[0]); acc[1] = fmaf(w1, a01.y, acc[1]);
        acc[2] = fmaf(w1, a23.x, acc[2]); acc[3] = fmaf(w1, a23.y, acc[3]);
        a01 = __half22float2(*(__half2*)&r2v.x); a23 = __half22float2(*(__half2*)&r2v.y);
        acc[0] = fmaf(w2, a01.x, acc[0]); acc[1] = fmaf(w2, a01.y, acc[1]);
        acc[2] = fmaf(w2, a23.x, acc[2]); acc[3] = fmaf(w2, a23.y, acc[3]);
        a01 = __half22float2(*(__half2*)&r3v.x); a23 = __half22float2(*(__half2*)&r3v.y);
        acc[0] = fmaf(w3, a01.x, acc[0]); acc[1] = fmaf(w3, a01.y, acc[1]);
        acc[2] = fmaf(w3, a23.x, acc[2]); acc[3] = fmaf(w3, a23.y, acc[3]);
    }
    for (; e + 1 < r1; e += 2) {
        int sa = RFL(col[e]), sb = RFL(col[e + 1]);
        float wa = dis[sa], wb = dis[sb];
        int   s = hf ? sb : sa; float w = hf ? wb : wa;
        uint2 rv = *(const uint2*)(g + (size_t)s * 128 + sl * 4);
        float2 a01 = __half22float2(*(__half2*)&rv.x);
        float2 a23 = __half22float2(*(__half2*)&rv.y);
        acc[0] = fmaf(w, a01.x, acc[0]); acc[1] = fmaf(w, a01.y, acc[1]);
        acc[2] = fmaf(w, a23.x, acc[2]); acc[3] = fmaf(w, a23.y, acc[3]);
    }
    if (e < r1) {                           // odd tail: half 1 contributes 0
        int sa = RFL(col[e]);
        float wa = dis[sa];
        float w = hf ? 0.f : wa;
        uint2 rv = *(const uint2*)(g + (size_t)sa * 128 + sl * 4);
        float2 a01 = __half22float2(*(__half2*)&rv.x);
        float2 a23 = __half22float2(*(__half2*)&rv.y);
        acc[0] = fmaf(w, a01.x, acc[0]); acc[1] = fmaf(w, a01.y, acc[1]);
        acc[2] = fmaf(w, a23.x, acc[2]); acc[3] = fmaf(w, a23.y, acc[3]);
    }
#pragma unroll
    for (int k = 0; k < 4; k++) acc[k] += __shfl_xor(acc[k], 32);
}

// fused GCN layer: block = 16 nodes (4 waves x 4 serial nodes).
// agg (+bias,relu) -> LDS rows -> mfma_f32_16x16x32_f16 -> gout (no bias).
__global__ __launch_bounds__(256) void k_aggmm(
        const __half* __restrict__ gin, const int2* __restrict__ rpe,
        const int* __restrict__ col, const float* __restrict__ dis,
        const float* __restrict__ bias, const __half* __restrict__ WT,
        __half* __restrict__ gout, int n) {
    __shared__ _Float16 sH[16 * 136];
    __shared__ _Float16 sO[16 * 136];
    int t = threadIdx.x;
    int wave = t >> 6, lane = t & 63;
    int hf = lane >> 5, sl = lane & 31;
    float4 bb = ((const float4*)bias)[sl];
#pragma unroll
    for (int i = 0; i < 4; i++) {
        int node = RFL(blockIdx.x * 16 + wave * 4 + i);
        if (node < n) {
            int2 re = rpe[node];
            int r0 = RFL(re.x);
            int r1 = RFL(re.y);
            float di = dis[node];
            float acc[4];
            agg_node4(gin, col, dis, r0, r1, node, di, hf, sl, acc);
            if (hf == 0) {
                int lr = wave * 4 + i;
                __half2 o01 = __floats2half2_rn(
                    fmaxf(fmaf(di, acc[0], bb.x), 0.f),
                    fmaxf(fmaf(di, acc[1], bb.y), 0.f));
                __half2 o23 = __floats2half2_rn(
                    fmaxf(fmaf(di, acc[2], bb.z), 0.f),
                    fmaxf(fmaf(di, acc[3], bb.w), 0.f));
                uint2 pk;
                pk.x = *(unsigned*)&o01; pk.y = *(unsigned*)&o23;
                *(uint2*)&sH[lr * 136 + sl * 4] = pk;
            }
        }
    }
    __syncthreads();
    // mm: wave covers cols [wave*32, wave*32+32) for all 16 rows
    int q = lane >> 4, c = lane & 15;
    int n0 = wave * 32;
    f32x4 acc0 = {0.f, 0.f, 0.f, 0.f}, acc1 = {0.f, 0.f, 0.f, 0.f};
#pragma unroll
    for (int ks = 0; ks < 4; ks++) {
        int k0 = ks * 32;
        half8 a  = *(half8*)&sH[c * 136 + k0 + q * 8];
        half8 b0 = *(const half8*)(WT + (size_t)(n0 + c) * 128 + k0 + q * 8);
        half8 b1 = *(const half8*)(WT + (size_t)(n0 + 16 + c) * 128 + k0 + q * 8);
        acc0 = __builtin_amdgcn_mfma_f32_16x16x32_f16(a, b0, acc0, 0, 0, 0);
        acc1 = __builtin_amdgcn_mfma_f32_16x16x32_f16(a, b1, acc1, 0, 0, 0);
    }
#pragma unroll
    for (int r = 0; r < 4; r++) {
        sO[(q * 4 + r) * 136 + n0 + c]      = (_Float16)acc0[r];
        sO[(q * 4 + r) * 136 + n0 + 16 + c] = (_Float16)acc1[r];
    }
    __syncthreads();
    int lr2 = t >> 4, seg = t & 15;
    int row = blockIdx.x * 16 + lr2;
    if (row < n)
        *(uint4*)(gout + (size_t)row * 128 + seg * 8) =
            *(uint4*)&sO[lr2 * 136 + seg * 8];
}

// fused layer-3 agg + mean-pool. Single-graph blocks (~92%): per-wave
// register partials -> private LDS slots (no LDS atomics) -> one barrier ->
// 128 global atomics per block. Boundary blocks: per-wave flush.
__global__ __launch_bounds__(256) void k_aggsum(
        const __half* __restrict__ gin, const int2* __restrict__ rpe,
        const int* __restrict__ col, const float* __restrict__ dis,
        const float* __restrict__ bias, const int* __restrict__ batch,
        float* __restrict__ sums, int n) {
    __shared__ float ls[4][128];
    int t = threadIdx.x;
    int wave = t >> 6, lane = t & 63;
    int hf = lane >> 5, sl = lane & 31;
    int nodeBase = blockIdx.x * 16;
    if (nodeBase >= n) return;
    int lastNode = min(nodeBase + 15, n - 1);
    int b0 = RFL(batch[nodeBase]);
    bool uni = (RFL(batch[lastNode]) == b0);
    float4 bb = ((const float4*)bias)[sl];
    float sx[4] = {0.f, 0.f, 0.f, 0.f};
    int curb = b0;
#pragma unroll
    for (int i = 0; i < 4; i++) {
        int node = RFL(nodeBase + wave * 4 + i);
        if (node < n) {
            int2 re = rpe[node];
            int r0 = RFL(re.x);
            int r1 = RFL(re.y);
            float di = dis[node];
            float acc[4];
            agg_node4(gin, col, dis, r0, r1, node, di, hf, sl, acc);
            float o0 = fmaxf(fmaf(di, acc[0], bb.x), 0.f);
            float o1 = fmaxf(fmaf(di, acc[1], bb.y), 0.f);
            float o2 = fmaxf(fmaf(di, acc[2], bb.z), 0.f);
            float o3 = fmaxf(fmaf(di, acc[3], bb.w), 0.f);
            if (!uni) {
                int b = RFL(batch[node]);
                if (b != curb) {
                    if (hf == 0) {
                        atomicAdd(&sums[(size_t)curb * 128 + sl * 4 + 0], sx[0]);
                        atomicAdd(&sums[(size_t)curb * 128 + sl * 4 + 1], sx[1]);
                        atomicAdd(&sums[(size_t)curb * 128 + sl * 4 + 2], sx[2]);
                        atomicAdd(&sums[(size_t)curb * 128 + sl * 4 + 3], sx[3]);
                    }
                    sx[0] = sx[1] = sx[2] = sx[3] = 0.f;
                    curb = b;
                }
            }
            sx[0] += o0; sx[1] += o1; sx[2] += o2; sx[3] += o3;
        }
    }
    if (uni) {
        // slot-exclusive LDS write (hf==0 lanes cover all 128 feats)
        if (hf == 0) {
            ls[wave][sl * 4 + 0] = sx[0];
            ls[wave][sl * 4 + 1] = sx[1];
            ls[wave][sl * 4 + 2] = sx[2];
            ls[wave][sl * 4 + 3] = sx[3];
        }
        __syncthreads();
        if (t < 128) {
            float v = ls[0][t] + ls[1][t] + ls[2][t] + ls[3][t];
            atomicAdd(&sums[(size_t)b0 * 128 + t], v);
        }
    } else {
        if (hf == 0) {
            atomicAdd(&sums[(size_t)curb * 128 + sl * 4 + 0], sx[0]);
            atomicAdd(&sums[(size_t)curb * 128 + sl * 4 + 1], sx[1]);
            atomicAdd(&sums[(size_t)curb * 128 + sl * 4 + 2], sx[2]);
            atomicAdd(&sums[(size_t)curb * 128 + sl * 4 + 3], sx[3]);
        }
    }
}

// head: pooled = sums/cnt; out = pooled @ Wd2 + bd2. One block per graph.
__global__ __launch_bounds__(128) void k_head(
        const float* __restrict__ sums, const int* __restrict__ gs,
        const float* __restrict__ Wd2, const float* __restrict__ bd2,
        float* __restrict__ out) {
    int gidx = blockIdx.x;
    int j = threadIdx.x;
    int c = gs[gidx + 1] - gs[gidx];
    float inv = 1.0f / (float)(c > 1 ? c : 1);
    __shared__ float sp[128];
    sp[j] = sums[(size_t)gidx * 128 + j] * inv;
    __syncthreads();
    float o = bd2[j];
#pragma unroll 8
    for (int k = 0; k < 128; k++) o = fmaf(sp[k], Wd2[k * 128 + j], o);
    out[gidx * 128 + j] = o;
}

extern "C" void kernel_launch(void* const* d_in, const int* in_sizes, int n_in,
                              void* d_out, int out_size, void* d_ws, size_t ws_size,
                              hipStream_t stream) {
    const float* x   = (const float*)d_in[0];
    const int*  ei   = (const int*)d_in[1];
    const int* batch = (const int*)d_in[2];
    const float* Wd1 = (const float*)d_in[3];
    const float* bd1 = (const float*)d_in[4];
    const float* Wg1 = (const float*)d_in[5];
    const float* bg1 = (const float*)d_in[6];
    const float* Wg2 = (const float*)d_in[7];
    const float* bg2 = (const float*)d_in[8];
    const float* Wg3 = (const float*)d_in[9];
    const float* bg3 = (const float*)d_in[10];
    const float* Wd2 = (const float*)d_in[11];
    const float* bd2 = (const float*)d_in[12];
    float* out = (float*)d_out;

    int N  = in_sizes[0] / 4;       // N_FEAT = 4
    int E  = in_sizes[1] / 2;       // edge_index is [2, E]
    int NG = out_size / 128;        // 512 graphs
    const int* srcIdx = ei;
    const int* dstIdx = ei + E;
    int nbkt = (N + BSZ - 1) >> BSHIFT;     // 391 for N=100000

    char* p = (char*)d_ws;
    auto alloc = [&](size_t bytes) -> char* {
        char* r = p;
        p += (bytes + 255) & ~(size_t)255;
        return r;
    };
    int*    bktFill = (int*)alloc((size_t)nbkt * CPAD * 4);
    int*    staged  = (int*)alloc(((size_t)nbkt << CAPSH) * 4);   // 12.8 MB
    int*    col     = (int*)alloc(((size_t)nbkt << CAPSH) * 4);   // 12.8 MB
    int2*   rpe     = (int2*)alloc((size_t)N * 8);
    float*  dis     = (float*)alloc((size_t)N * 4);
    int*    gs      = (int*)alloc(((size_t)NG + 1) * 4);
    float*  sums    = (float*)alloc((size_t)NG * 128 * 4);
    __half* WT2     = (__half*)alloc(16384 * 2);
    __half* WT3     = (__half*)alloc(16384 * 2);
    __half* gA      = (__half*)alloc((size_t)N * 128 * 2);
    __half* gB      = (__half*)alloc((size_t)N * 128 * 2);
    (void)ws_size; (void)n_in;

    int BINB = (E + 4095) / 4096;               // 391
    int L1B  = (N + 63) / 64;                   // 1563
    int NB1  = (N + 511) / 512;                 // 196
    int ZB   = (NG * 128 + 511) / 512;          // 128
    int prepB = BINB + L1B + 32 + NB1 + ZB;
    int fb   = (N + 15) / 16;                   // 6250

    hipMemsetAsync(bktFill, 0, (size_t)nbkt * CPAD * 4, stream);  // 50 KB

    k_prep<<<prepB, 512, 0, stream>>>(x, Wd1, bd1, Wg1, gA, Wg2, Wg3, WT2, WT3,
                                      batch, gs, srcIdx, dstIdx, bktFill,
                                      staged, sums, N, NG, E, nbkt,
                                      BINB, L1B, NB1);
    k_fineB<<<nbkt, 512, 0, stream>>>(staged, bktFill, rpe, dis, col, N);

    k_aggmm<<<fb, 256, 0, stream>>>(gA, rpe, col, dis, bg1, WT2, gB, N);
    k_aggmm<<<fb, 256, 0, stream>>>(gB, rpe, col, dis, bg2, WT3, gA, N);
    k_aggsum<<<fb, 256, 0, stream>>>(gA, rpe, col, dis, bg3, batch, sums, N);

    k_head<<<NG, 128, 0, stream>>>(sums, gs, Wd2, bd2, out);
}

// Round 17
// 356.835 us; speedup vs baseline: 1.0992x; 1.0070x over previous
//
#include <hip/hip_runtime.h>
#include <hip/hip_fp16.h>

// ---------------------------------------------------------------------------
// FormulaNet GCN forward: 3x GCNConv(128) + mean-pool(512 graphs) + dense.
// R2: fp16 node tensors (fp32 math). R4: bucket-sort CSR. R6: MFMA mm.
// R7: prep mega-kernel. R8: deep fusion (aggmm/aggsum). R10: paired-edge
// gathers. R12: aggsum block pooling via private LDS slots. R15: layer1
// amortized to 64 nodes/block. [BEST 359.3]
// R16: fineB occupancy + LDS bucket cache: 1024 thr/block (391 blocks were
//      1.5/CU = 12 waves/CU, the k_pool-R5 under-occupancy signature) and a
//      fused load+hist pass staging all <=8192 bucket entries in LDS (32 KB)
//      so the scatter pass reads LDS, not global (-6.4 MB, -1 barrier).
//      Bucket geometry untouched (R11 confound). Agg family is at its
//      5-probe fused floor: FETCH = compulsory 201 MB/layer (8 XCD x 25.6 MB),
//      fill ~2.83 TB/s vs 2.94 best-ever standalone.
// ---------------------------------------------------------------------------

#define BSHIFT 8
#define BSZ    256          // nodes per bucket
#define MAXBKT 512          // LDS sizing bound (N <= 131072)
#define CPAD   32           // 1 counter / 128 B line for global cursors
#define CAPSH  13           // 8192 staged/col slots per bucket

typedef _Float16 half8 __attribute__((ext_vector_type(8)));
typedef float f32x4 __attribute__((ext_vector_type(4)));

#define RFL __builtin_amdgcn_readfirstlane

// ---- prep: bin | layer1 | cvtW | bounds | zero(sums), by block range ----
__global__ __launch_bounds__(512) void k_prep(
        const float* __restrict__ x, const float* __restrict__ Wd1,
        const float* __restrict__ bd1, const float* __restrict__ Wg1,
        __half* __restrict__ g,
        const float* __restrict__ W2, const float* __restrict__ W3,
        __half* __restrict__ WT2, __half* __restrict__ WT3,
        const int* __restrict__ batch, int* __restrict__ gs,
        const int* __restrict__ src, const int* __restrict__ dst,
        int* __restrict__ bktFill, int* __restrict__ staged,
        float* __restrict__ sums,
        int N, int NG, int E, int nbkt, int BINB, int L1B, int NB1) {
    __shared__ float sW[512];
    __shared__ int hh[MAXBKT], base[MAXBKT], cur[MAXBKT];
    int bid = blockIdx.x;
    int t = threadIdx.x;
    if (bid < BINB) {
        // ---- bin: 4096 edges/block; LDS hist -> reservation -> scatter
        for (int i = t; i < nbkt; i += 512) { hh[i] = 0; cur[i] = 0; }
        __syncthreads();
        int e0 = bid * 4096 + t;
#pragma unroll
        for (int k = 0; k < 8; k++) {
            int e = e0 + k * 512;
            if (e < E) atomicAdd(&hh[dst[e] >> BSHIFT], 1);
        }
        __syncthreads();
        for (int i = t; i < nbkt; i += 512)
            base[i] = hh[i] ? atomicAdd(&bktFill[(size_t)i * CPAD], hh[i]) : 0;
        __syncthreads();
#pragma unroll
        for (int k = 0; k < 8; k++) {
            int e = e0 + k * 512;
            if (e < E) {
                int d = dst[e], s = src[e];
                int b = d >> BSHIFT;
                int off = atomicAdd(&cur[b], 1);
                staged[((size_t)b << CAPSH) + base[b] + off] =
                    ((d & (BSZ - 1)) << 17) | s;
            }
        }
    } else if (bid < BINB + L1B) {
        // ---- layer1: 64 nodes/block; h0 = relu(x@Wd1+bd1); g = h0@Wg1
        int rb = bid - BINB;
        sW[t] = Wg1[t];
        __syncthreads();
        int j = t & 127;
#pragma unroll 4
        for (int it = 0; it < 16; ++it) {
            int node = rb * 64 + it * 4 + (t >> 7);
            if (node < N) {
                float4 xv = ((const float4*)x)[node];
                float acc = 0.f;
#pragma unroll
                for (int k = 0; k < 4; k++) {
                    float h0 = xv.x * Wd1[k] + xv.y * Wd1[4 + k]
                             + xv.z * Wd1[8 + k] + xv.w * Wd1[12 + k] + bd1[k];
                    h0 = fmaxf(h0, 0.f);
                    acc = fmaf(h0, sW[k * 128 + j], acc);
                }
                g[(size_t)node * 128 + j] = __float2half_rn(acc);
            }
        }
    } else if (bid < BINB + L1B + 32) {
        // ---- cvtW: W fp32 [k][n] -> WT fp16 [n][k], both layers
        int t2 = (bid - BINB - L1B) * 512 + t;      // 0..16383
        int k = t2 >> 7, nn = t2 & 127;
        WT2[nn * 128 + k] = __float2half_rn(W2[t2]);
        WT3[nn * 128 + k] = __float2half_rn(W3[t2]);
    } else if (bid < BINB + L1B + 32 + NB1) {
        // ---- bounds: batch sorted -> per-graph node ranges
        int i = (bid - BINB - L1B - 32) * 512 + t;
        if (i >= N) return;
        int b = batch[i];
        int prev = (i == 0) ? -1 : batch[i - 1];
        for (int g2 = prev + 1; g2 <= b; ++g2) gs[g2] = i;
        if (i == N - 1)
            for (int g2 = b + 1; g2 <= NG; ++g2) gs[g2] = N;
    } else {
        // ---- zero sums
        int idx = (bid - BINB - L1B - 32 - NB1) * 512 + t;
        if (idx < NG * 128) sums[idx] = 0.f;
    }
}

// ---- per-bucket: fused load+hist into LDS cache -> scan -> LDS scatter ----
__global__ __launch_bounds__(1024) void k_fineB(
        const int* __restrict__ staged, const int* __restrict__ bktFill,
        int2* __restrict__ rpe, float* __restrict__ dis,
        int* __restrict__ col, int N) {
    __shared__ int sEnt[1 << CAPSH];        // 32 KB bucket cache
    __shared__ int cnt[BSZ];
    __shared__ int incl[BSZ];
    int b = blockIdx.x;
    int lo = b << CAPSH;
    int cntE = bktFill[(size_t)b * CPAD];
    int n0 = b << BSHIFT;
    int tid = threadIdx.x;
    if (tid < BSZ) cnt[tid] = 0;
    __syncthreads();
    // fused: stage entries in LDS + histogram
    for (int e = tid; e < cntE; e += 1024) {
        int v = staged[lo + e];
        sEnt[e] = v;
        atomicAdd(&cnt[v >> 17], 1);
    }
    __syncthreads();
    int v = 0;
    if (tid < BSZ) { v = cnt[tid]; incl[tid] = v; }
    for (int off = 1; off < BSZ; off <<= 1) {
        __syncthreads();
        int t = (tid < BSZ && tid >= off) ? incl[tid - off] : 0;
        __syncthreads();
        if (tid < BSZ) incl[tid] += t;
    }
    __syncthreads();
    int myofs = 0;
    if (tid < BSZ) {
        myofs = incl[tid] - v;                 // exclusive
        int node = n0 + tid;
        if (node < N) {
            rpe[node] = make_int2(lo + myofs, lo + myofs + v);
            dis[node] = rsqrtf((float)(v + 1));    // +1: self-loop
        }
    }
    __syncthreads();
    // reuse incl[] as base table, cnt[] as cursors
    if (tid < BSZ) { incl[tid] = myofs; cnt[tid] = 0; }
    __syncthreads();
    for (int e = tid; e < cntE; e += 1024) {
        int ent = sEnt[e];
        int dl = ent >> 17;
        int pos = lo + incl[dl] + atomicAdd(&cnt[dl], 1);
        col[pos] = ent & 0x1FFFF;
    }
}

// paired-edge aggregation: half-wave hf covers edge e+hf's FULL row
// (8 B/lane = ushort4, lanes sl=0..31 -> feats 4sl..4sl+3).
// After the loop, shfl_xor(32) combines halves; all lanes hold the sum.
__device__ __forceinline__ void agg_node4(
        const __half* __restrict__ g, const int* __restrict__ col,
        const float* __restrict__ dis, int r0, int r1, int node,
        float di, int hf, int sl, float acc[4]) {
    uint2 mr = *(const uint2*)(g + (size_t)node * 128 + sl * 4);
    float2 m01 = __half22float2(*(__half2*)&mr.x);
    float2 m23 = __half22float2(*(__half2*)&mr.y);
    float sw = hf ? 0.f : di;               // self-loop on half 0 only
    acc[0] = sw * m01.x; acc[1] = sw * m01.y;
    acc[2] = sw * m23.x; acc[3] = sw * m23.y;
    int e = r0;
    for (; e + 7 < r1; e += 8) {            // 4 pairs in flight
        int sa0 = RFL(col[e]),     sb0 = RFL(col[e + 1]);
        int sa1 = RFL(col[e + 2]), sb1 = RFL(col[e + 3]);
        int sa2 = RFL(col[e + 4]), sb2 = RFL(col[e + 5]);
        int sa3 = RFL(col[e + 6]), sb3 = RFL(col[e + 7]);
        float wa0 = dis[sa0], wb0 = dis[sb0], wa1 = dis[sa1], wb1 = dis[sb1];
        float wa2 = dis[sa2], wb2 = dis[sb2], wa3 = dis[sa3], wb3 = dis[sb3];
        int   s0 = hf ? sb0 : sa0; float w0 = hf ? wb0 : wa0;
        int   s1 = hf ? sb1 : sa1; float w1 = hf ? wb1 : wa1;
        int   s2 = hf ? sb2 : sa2; float w2 = hf ? wb2 : wa2;
        int   s3 = hf ? sb3 : sa3; float w3 = hf ? wb3 : wa3;
        uint2 r0v = *(const uint2*)(g + (size_t)s0 * 128 + sl * 4);
        uint2 r1v = *(const uint2*)(g + (size_t)s1 * 128 + sl * 4);
        uint2 r2v = *(const uint2*)(g + (size_t)s2 * 128 + sl * 4);
        uint2 r3v = *(const uint2*)(g + (size_t)s3 * 128 + sl * 4);
        float2 a01, a23;
        a01 = __half22float2(*(__half2*)&r0v.x); a23 = __half22float2(*(__half2*)&r0v.y);
        acc[0] = fmaf(w0, a01.x, acc[0]); acc[1] = fmaf(w0, a01.y, acc[1]);
        acc[2] = fmaf(w0, a23.x, acc[2]); acc[3] = fmaf(w0, a23.y, acc[3]);
        a01 = __half22float2(*(__half2*)&r1v.x); a23 = __half22float2(*(__half2*)&r1v.y);
        acc[0] = fmaf(w1, a01.x, acc[0]); acc[1] = fmaf(w1, a01.y, acc[1]);
        acc[2] = fmaf(w1, a23.x, acc[2]); acc[3] = fmaf(w1, a23.y, acc[3]);
        a01 = __half22float2(*(__half2*)&r2v.x); a23 = __half22float2(*(__half2*)&r2v.y);
        acc[0] = fmaf(w2, a01.x, acc[0]); acc[1] = fmaf(w2, a01.y, acc[1]);
        acc[2] = fmaf(w2, a23.x, acc[2]); acc[3] = fmaf(w2, a23.y, acc[3]);
        a01 = __half22float2(*(__half2*)&r3v.x); a23 = __half22float2(*(__half2*)&r3v.y);
        acc[0] = fmaf(w3, a01.x, acc[0]); acc[1] = fmaf(w3, a01.y, acc[1]);
        acc[2] = fmaf(w3, a23.x, acc[2]); acc[3] = fmaf(w3, a23.y, acc[3]);
    }
    for (; e + 1 < r1; e += 2) {
        int sa = RFL(col[e]), sb = RFL(col[e + 1]);
        float wa = dis[sa], wb = dis[sb];
        int   s = hf ? sb : sa; float w = hf ? wb : wa;
        uint2 rv = *(const uint2*)(g + (size_t)s * 128 + sl * 4);
        float2 a01 = __half22float2(*(__half2*)&rv.x);
        float2 a23 = __half22float2(*(__half2*)&rv.y);
        acc[0] = fmaf(w, a01.x, acc[0]); acc[1] = fmaf(w, a01.y, acc[1]);
        acc[2] = fmaf(w, a23.x, acc[2]); acc[3] = fmaf(w, a23.y, acc[3]);
    }
    if (e < r1) {                           // odd tail: half 1 contributes 0
        int sa = RFL(col[e]);
        float wa = dis[sa];
        float w = hf ? 0.f : wa;
        uint2 rv = *(const uint2*)(g + (size_t)sa * 128 + sl * 4);
        float2 a01 = __half22float2(*(__half2*)&rv.x);
        float2 a23 = __half22float2(*(__half2*)&rv.y);
        acc[0] = fmaf(w, a01.x, acc[0]); acc[1] = fmaf(w, a01.y, acc[1]);
        acc[2] = fmaf(w, a23.x, acc[2]); acc[3] = fmaf(w, a23.y, acc[3]);
    }
#pragma unroll
    for (int k = 0; k < 4; k++) acc[k] += __shfl_xor(acc[k], 32);
}

// fused GCN layer: block = 16 nodes (4 waves x 4 serial nodes).
// agg (+bias,relu) -> LDS rows -> mfma_f32_16x16x32_f16 -> gout (no bias).
__global__ __launch_bounds__(256) void k_aggmm(
        const __half* __restrict__ gin, const int2* __restrict__ rpe,
        const int* __restrict__ col, const float* __restrict__ dis,
        const float* __restrict__ bias, const __half* __restrict__ WT,
        __half* __restrict__ gout, int n) {
    __shared__ _Float16 sH[16 * 136];
    __shared__ _Float16 sO[16 * 136];
    int t = threadIdx.x;
    int wave = t >> 6, lane = t & 63;
    int hf = lane >> 5, sl = lane & 31;
    float4 bb = ((const float4*)bias)[sl];
#pragma unroll
    for (int i = 0; i < 4; i++) {
        int node = RFL(blockIdx.x * 16 + wave * 4 + i);
        if (node < n) {
            int2 re = rpe[node];
            int r0 = RFL(re.x);
            int r1 = RFL(re.y);
            float di = dis[node];
            float acc[4];
            agg_node4(gin, col, dis, r0, r1, node, di, hf, sl, acc);
            if (hf == 0) {
                int lr = wave * 4 + i;
                __half2 o01 = __floats2half2_rn(
                    fmaxf(fmaf(di, acc[0], bb.x), 0.f),
                    fmaxf(fmaf(di, acc[1], bb.y), 0.f));
                __half2 o23 = __floats2half2_rn(
                    fmaxf(fmaf(di, acc[2], bb.z), 0.f),
                    fmaxf(fmaf(di, acc[3], bb.w), 0.f));
                uint2 pk;
                pk.x = *(unsigned*)&o01; pk.y = *(unsigned*)&o23;
                *(uint2*)&sH[lr * 136 + sl * 4] = pk;
            }
        }
    }
    __syncthreads();
    // mm: wave covers cols [wave*32, wave*32+32) for all 16 rows
    int q = lane >> 4, c = lane & 15;
    int n0 = wave * 32;
    f32x4 acc0 = {0.f, 0.f, 0.f, 0.f}, acc1 = {0.f, 0.f, 0.f, 0.f};
#pragma unroll
    for (int ks = 0; ks < 4; ks++) {
        int k0 = ks * 32;
        half8 a  = *(half8*)&sH[c * 136 + k0 + q * 8];
        half8 b0 = *(const half8*)(WT + (size_t)(n0 + c) * 128 + k0 + q * 8);
        half8 b1 = *(const half8*)(WT + (size_t)(n0 + 16 + c) * 128 + k0 + q * 8);
        acc0 = __builtin_amdgcn_mfma_f32_16x16x32_f16(a, b0, acc0, 0, 0, 0);
        acc1 = __builtin_amdgcn_mfma_f32_16x16x32_f16(a, b1, acc1, 0, 0, 0);
    }
#pragma unroll
    for (int r = 0; r < 4; r++) {
        sO[(q * 4 + r) * 136 + n0 + c]      = (_Float16)acc0[r];
        sO[(q * 4 + r) * 136 + n0 + 16 + c] = (_Float16)acc1[r];
    }
    __syncthreads();
    int lr2 = t >> 4, seg = t & 15;
    int row = blockIdx.x * 16 + lr2;
    if (row < n)
        *(uint4*)(gout + (size_t)row * 128 + seg * 8) =
            *(uint4*)&sO[lr2 * 136 + seg * 8];
}

// fused layer-3 agg + mean-pool. Single-graph blocks (~92%): per-wave
// register partials -> private LDS slots (no LDS atomics) -> one barrier ->
// 128 global atomics per block. Boundary blocks: per-wave flush.
__global__ __launch_bounds__(256) void k_aggsum(
        const __half* __restrict__ gin, const int2* __restrict__ rpe,
        const int* __restrict__ col, const float* __restrict__ dis,
        const float* __restrict__ bias, const int* __restrict__ batch,
        float* __restrict__ sums, int n) {
    __shared__ float ls[4][128];
    int t = threadIdx.x;
    int wave = t >> 6, lane = t & 63;
    int hf = lane >> 5, sl = lane & 31;
    int nodeBase = blockIdx.x * 16;
    if (nodeBase >= n) return;
    int lastNode = min(nodeBase + 15, n - 1);
    int b0 = RFL(batch[nodeBase]);
    bool uni = (RFL(batch[lastNode]) == b0);
    float4 bb = ((const float4*)bias)[sl];
    float sx[4] = {0.f, 0.f, 0.f, 0.f};
    int curb = b0;
#pragma unroll
    for (int i = 0; i < 4; i++) {
        int node = RFL(nodeBase + wave * 4 + i);
        if (node < n) {
            int2 re = rpe[node];
            int r0 = RFL(re.x);
            int r1 = RFL(re.y);
            float di = dis[node];
            float acc[4];
            agg_node4(gin, col, dis, r0, r1, node, di, hf, sl, acc);
            float o0 = fmaxf(fmaf(di, acc[0], bb.x), 0.f);
            float o1 = fmaxf(fmaf(di, acc[1], bb.y), 0.f);
            float o2 = fmaxf(fmaf(di, acc[2], bb.z), 0.f);
            float o3 = fmaxf(fmaf(di, acc[3], bb.w), 0.f);
            if (!uni) {
                int b = RFL(batch[node]);
                if (b != curb) {
                    if (hf == 0) {
                        atomicAdd(&sums[(size_t)curb * 128 + sl * 4 + 0], sx[0]);
                        atomicAdd(&sums[(size_t)curb * 128 + sl * 4 + 1], sx[1]);
                        atomicAdd(&sums[(size_t)curb * 128 + sl * 4 + 2], sx[2]);
                        atomicAdd(&sums[(size_t)curb * 128 + sl * 4 + 3], sx[3]);
                    }
                    sx[0] = sx[1] = sx[2] = sx[3] = 0.f;
                    curb = b;
                }
            }
            sx[0] += o0; sx[1] += o1; sx[2] += o2; sx[3] += o3;
        }
    }
    if (uni) {
        // slot-exclusive LDS write (hf==0 lanes cover all 128 feats)
        if (hf == 0) {
            ls[wave][sl * 4 + 0] = sx[0];
            ls[wave][sl * 4 + 1] = sx[1];
            ls[wave][sl * 4 + 2] = sx[2];
            ls[wave][sl * 4 + 3] = sx[3];
        }
        __syncthreads();
        if (t < 128) {
            float v = ls[0][t] + ls[1][t] + ls[2][t] + ls[3][t];
            atomicAdd(&sums[(size_t)b0 * 128 + t], v);
        }
    } else {
        if (hf == 0) {
            atomicAdd(&sums[(size_t)curb * 128 + sl * 4 + 0], sx[0]);
            atomicAdd(&sums[(size_t)curb * 128 + sl * 4 + 1], sx[1]);
            atomicAdd(&sums[(size_t)curb * 128 + sl * 4 + 2], sx[2]);
            atomicAdd(&sums[(size_t)curb * 128 + sl * 4 + 3], sx[3]);
        }
    }
}

// head: pooled = sums/cnt; out = pooled @ Wd2 + bd2. One block per graph.
__global__ __launch_bounds__(128) void k_head(
        const float* __restrict__ sums, const int* __restrict__ gs,
        const float* __restrict__ Wd2, const float* __restrict__ bd2,
        float* __restrict__ out) {
    int gidx = blockIdx.x;
    int j = threadIdx.x;
    int c = gs[gidx + 1] - gs[gidx];
    float inv = 1.0f / (float)(c > 1 ? c : 1);
    __shared__ float sp[128];
    sp[j] = sums[(size_t)gidx * 128 + j] * inv;
    __syncthreads();
    float o = bd2[j];
#pragma unroll 8
    for (int k = 0; k < 128; k++) o = fmaf(sp[k], Wd2[k * 128 + j], o);
    out[gidx * 128 + j] = o;
}

extern "C" void kernel_launch(void* const* d_in, const int* in_sizes, int n_in,
                              void* d_out, int out_size, void* d_ws, size_t ws_size,
                              hipStream_t stream) {
    const float* x   = (const float*)d_in[0];
    const int*  ei   = (const int*)d_in[1];
    const int* batch = (const int*)d_in[2];
    const float* Wd1 = (const float*)d_in[3];
    const float* bd1 = (const float*)d_in[4];
    const float* Wg1 = (const float*)d_in[5];
    const float* bg1 = (const float*)d_in[6];
    const float* Wg2 = (const float*)d_in[7];
    const float* bg2 = (const float*)d_in[8];
    const float* Wg3 = (const float*)d_in[9];
    const float* bg3 = (const float*)d_in[10];
    const float* Wd2 = (const float*)d_in[11];
    const float* bd2 = (const float*)d_in[12];
    float* out = (float*)d_out;

    int N  = in_sizes[0] / 4;       // N_FEAT = 4
    int E  = in_sizes[1] / 2;       // edge_index is [2, E]
    int NG = out_size / 128;        // 512 graphs
    const int* srcIdx = ei;
    const int* dstIdx = ei + E;
    int nbkt = (N + BSZ - 1) >> BSHIFT;     // 391 for N=100000

    char* p = (char*)d_ws;
    auto alloc = [&](size_t bytes) -> char* {
        char* r = p;
        p += (bytes + 255) & ~(size_t)255;
        return r;
    };
    int*    bktFill = (int*)alloc((size_t)nbkt * CPAD * 4);
    int*    staged  = (int*)alloc(((size_t)nbkt << CAPSH) * 4);   // 12.8 MB
    int*    col     = (int*)alloc(((size_t)nbkt << CAPSH) * 4);   // 12.8 MB
    int2*   rpe     = (int2*)alloc((size_t)N * 8);
    float*  dis     = (float*)alloc((size_t)N * 4);
    int*    gs      = (int*)alloc(((size_t)NG + 1) * 4);
    float*  sums    = (float*)alloc((size_t)NG * 128 * 4);
    __half* WT2     = (__half*)alloc(16384 * 2);
    __half* WT3     = (__half*)alloc(16384 * 2);
    __half* gA      = (__half*)alloc((size_t)N * 128 * 2);
    __half* gB      = (__half*)alloc((size_t)N * 128 * 2);
    (void)ws_size; (void)n_in;

    int BINB = (E + 4095) / 4096;               // 391
    int L1B  = (N + 63) / 64;                   // 1563
    int NB1  = (N + 511) / 512;                 // 196
    int ZB   = (NG * 128 + 511) / 512;          // 128
    int prepB = BINB + L1B + 32 + NB1 + ZB;
    int fb   = (N + 15) / 16;                   // 6250

    hipMemsetAsync(bktFill, 0, (size_t)nbkt * CPAD * 4, stream);  // 50 KB

    k_prep<<<prepB, 512, 0, stream>>>(x, Wd1, bd1, Wg1, gA, Wg2, Wg3, WT2, WT3,
                                      batch, gs, srcIdx, dstIdx, bktFill,
                                      staged, sums, N, NG, E, nbkt,
                                      BINB, L1B, NB1);
    k_fineB<<<nbkt, 1024, 0, stream>>>(staged, bktFill, rpe, dis, col, N);

    k_aggmm<<<fb, 256, 0, stream>>>(gA, rpe, col, dis, bg1, WT2, gB, N);
    k_aggmm<<<fb, 256, 0, stream>>>(gB, rpe, col, dis, bg2, WT3, gA, N);
    k_aggsum<<<fb, 256, 0, stream>>>(gA, rpe, col, dis, bg3, batch, sums, N);

    k_head<<<NG, 128, 0, stream>>>(sums, gs, Wd2, bd2, out);
}